// Round 3
// baseline (2512.916 us; speedup 1.0000x reference)
//
#include <hip/hip_runtime.h>

// EAM force: 3 kernels.
//  K0: zero rho (ws) and forces (d_out)
//  K1 (per pair): density interp -> atomicAdd rho[i], rho[j]
//  K2 (per pair): recompute dF(rho) inline; coeff -> atomicAdd forces
//
// CRITICAL numerics: all scalar constants are computed in f64 on host and
// rounded ONCE to f32, mirroring Python-f64-scalar -> jnp f32 cast semantics.
// (rclip computed as 6.0f*(1.0f-1e-7f) is 1 ulp lower than f32(6.0*(1.0-1e-7));
// with 99.6% of pairs clipped to r_max this coherent 1-ulp shift amplified
// through rho->F' to a 0.625 absmax error in rounds 1-2.)

#define EAM_BLOCK 256

__device__ __forceinline__ float interp_row(const float* __restrict__ row,
                                            int i0, int i1, float fr) {
    float a = row[i0];
    float b = row[i1];
    return a + fr * (b - a);
}

__device__ __forceinline__ float embed_dF(float rho, int t,
                                          const float* __restrict__ embed_tab,
                                          const float* __restrict__ rho_min_t,
                                          const float* __restrict__ inv_drho_t,
                                          int n_rho, float one_m_eps) {
    float rmin = rho_min_t[t];
    float invd = inv_drho_t[t];
    // hi = rmin + (n_rho-1)/invd * (1-EPS), all f32 ops like the reference
    float hi = rmin + (float)(n_rho - 1) / invd * one_m_eps;
    float rc = fminf(fmaxf(rho, rmin), hi);
    float g  = (rc - rmin) * invd;
    int  g0  = (int)g;
    g0 = g0 < 0 ? 0 : (g0 > n_rho - 2 ? n_rho - 2 : g0);
    float gfr = g - (float)g0;
    const float* row = embed_tab + (size_t)t * n_rho;
    float e0 = row[g0];
    float e1 = row[g0 + 1];
    return e0 + gfr * (e1 - e0);
}

__global__ void eam_zero_kernel(float* __restrict__ rho,
                                float* __restrict__ forces, int N) {
    int idx = blockIdx.x * blockDim.x + threadIdx.x;
    if (idx < N) rho[idx] = 0.0f;
    if (idx < 3 * N) forces[idx] = 0.0f;
}

__device__ __forceinline__ void pair_geom(
    const float* __restrict__ pos, int i, int j,
    float inv_dr, float rclip,
    float& dx, float& dy, float& dz, float& r,
    int& i0, int& i1, float& fr, int n_r)
{
#pragma clang fp contract(off)
    float xi = pos[3 * i + 0], yi = pos[3 * i + 1], zi = pos[3 * i + 2];
    float xj = pos[3 * j + 0], yj = pos[3 * j + 1], zj = pos[3 * j + 2];
    dx = xj - xi; dy = yj - yi; dz = zj - zi;
    float s = dx * dx;
    s = s + dy * dy;
    s = s + dz * dz;
    s = s + 1e-12f;
    r = sqrtf(s);

    float rc = fminf(fmaxf(r, 0.0f), rclip);
    float f  = rc * inv_dr;
    i0 = (int)f;
    fr = f - (float)i0;
    i1 = min(i0 + 1, n_r - 1);
}

__global__ void eam_density_kernel(
    const int* __restrict__ edge_i, const int* __restrict__ edge_j,
    const int* __restrict__ types, const float* __restrict__ pos,
    const float* __restrict__ dens_tab, int n_r, float inv_dr, float rclip,
    float* __restrict__ rho, int P)
{
    int p = blockIdx.x * blockDim.x + threadIdx.x;
    if (p >= P) return;

    int i = edge_i[p];
    int j = edge_j[p];

    float dx, dy, dz, r, fr;
    int i0, i1;
    pair_geom(pos, i, j, inv_dr, rclip, dx, dy, dz, r, i0, i1, fr, n_r);

    int ti = types[i];
    int tj = types[j];

    float dens_j = interp_row(dens_tab + (size_t)tj * n_r, i0, i1, fr);
    float dens_i = interp_row(dens_tab + (size_t)ti * n_r, i0, i1, fr);

    atomicAdd(&rho[i], dens_j);
    atomicAdd(&rho[j], dens_i);
}

__global__ void eam_force_kernel(
    const int* __restrict__ edge_i, const int* __restrict__ edge_j,
    const int* __restrict__ types, const float* __restrict__ pos,
    const float* __restrict__ dens_deriv_tab,   // [E, n_r]
    const float* __restrict__ pair_deriv_tab,   // [E, E, n_r]
    const float* __restrict__ rho,
    const float* __restrict__ embed_tab,        // [E, n_rho]
    const float* __restrict__ rho_min_t, const float* __restrict__ inv_drho_t,
    int n_r, int n_rho, int E, float inv_dr, float rclip, float one_m_eps,
    float* __restrict__ forces, int P)
{
    int p = blockIdx.x * blockDim.x + threadIdx.x;
    if (p >= P) return;

    int i = edge_i[p];
    int j = edge_j[p];

    float dx, dy, dz, r, fr;
    int i0, i1;
    pair_geom(pos, i, j, inv_dr, rclip, dx, dy, dz, r, i0, i1, fr, n_r);

    int ti = types[i];
    int tj = types[j];

    float ddens_j = interp_row(dens_deriv_tab + (size_t)tj * n_r, i0, i1, fr);
    float ddens_i = interp_row(dens_deriv_tab + (size_t)ti * n_r, i0, i1, fr);
    float dphi    = interp_row(pair_deriv_tab + ((size_t)ti * E + tj) * n_r, i0, i1, fr);

    float dFi = embed_dF(rho[i], ti, embed_tab, rho_min_t, inv_drho_t, n_rho, one_m_eps);
    float dFj = embed_dF(rho[j], tj, embed_tab, rho_min_t, inv_drho_t, n_rho, one_m_eps);

    float coeff = dFi * ddens_j + dFj * ddens_i + dphi;

    float fx = coeff * (dx / r);
    float fy = coeff * (dy / r);
    float fz = coeff * (dz / r);

    atomicAdd(&forces[3 * i + 0], -fx);
    atomicAdd(&forces[3 * i + 1], -fy);
    atomicAdd(&forces[3 * i + 2], -fz);
    atomicAdd(&forces[3 * j + 0],  fx);
    atomicAdd(&forces[3 * j + 1],  fy);
    atomicAdd(&forces[3 * j + 2],  fz);
}

extern "C" void kernel_launch(void* const* d_in, const int* in_sizes, int n_in,
                              void* d_out, int out_size, void* d_ws, size_t ws_size,
                              hipStream_t stream) {
    const float* positions        = (const float*)d_in[0];
    const float* density_table    = (const float*)d_in[1];
    const float* density_deriv    = (const float*)d_in[2];
    const float* pair_deriv       = (const float*)d_in[3];
    const float* embed_deriv      = (const float*)d_in[4];
    const float* embed_rho_min    = (const float*)d_in[5];
    const float* embed_inv_drho   = (const float*)d_in[6];
    const int*   atom_types       = (const int*)d_in[7];
    const int*   edge_i           = (const int*)d_in[8];
    const int*   edge_j           = (const int*)d_in[9];

    const int E     = in_sizes[5];
    const int N     = in_sizes[7];
    const int P     = in_sizes[8];
    const int n_r   = in_sizes[1] / E;
    const int n_rho = in_sizes[4] / E;

    // f64 host math, single rounding to f32 — mirrors Python-scalar semantics.
    const double R_MAX_d = 6.0;
    const double EPS_d   = 1e-7;
    const float inv_dr    = (float)((double)(n_r - 1) / R_MAX_d);   // f32(1365.1666...)
    const float rclip     = (float)(R_MAX_d * (1.0 - EPS_d));       // f32(5.9999994) = 5.99999952316
    const float one_m_eps = (float)(1.0 - EPS_d);                   // f32(0.9999999)

    float* rho    = (float*)d_ws;       // N floats
    float* forces = (float*)d_out;      // 3N floats

    int zero_blocks = (3 * N + EAM_BLOCK - 1) / EAM_BLOCK;
    int pair_blocks = (P + EAM_BLOCK - 1) / EAM_BLOCK;

    eam_zero_kernel<<<zero_blocks, EAM_BLOCK, 0, stream>>>(rho, forces, N);

    eam_density_kernel<<<pair_blocks, EAM_BLOCK, 0, stream>>>(
        edge_i, edge_j, atom_types, positions,
        density_table, n_r, inv_dr, rclip, rho, P);

    eam_force_kernel<<<pair_blocks, EAM_BLOCK, 0, stream>>>(
        edge_i, edge_j, atom_types, positions,
        density_deriv, pair_deriv, rho,
        embed_deriv, embed_rho_min, embed_inv_drho,
        n_r, n_rho, E, inv_dr, rclip, one_m_eps, forces, P);
}